// Round 2
// baseline (752.180 us; speedup 1.0000x reference)
//
#include <hip/hip_runtime.h>

#define WIDTH   640
#define HEIGHT  384
#define PLANE   (WIDTH*HEIGHT)
#define STRIP_H 24
#define NSTRIP  16                /* 384/24 */
#define GROUPS  12                /* STRIP_H/2 */
#define NBLK    (96*NSTRIP)       /* 1536 = 6 blocks/CU exactly */
#define CS_W    656               /* slots 0..649 used, slot = x+5 */
#define SSIM_C1 1.0e-4f
#define SSIM_C2 9.0e-4f
#define INV_N   (1.0f/23592960.0f)

typedef __fp16 h2v __attribute__((ext_vector_type(2)));

__device__ __forceinline__ unsigned packh2(float a, float b) {
    // single v_cvt_pkrtz_f16_f32; rtz quantization is consistent add/sub so no drift
    h2v v = __builtin_amdgcn_cvt_pkrtz(a, b);
    unsigned r; __builtin_memcpy(&r, &v, 4); return r;
}
__device__ __forceinline__ float2 unpackh2(unsigned u) {
    h2v v; __builtin_memcpy(&v, &u, 4);
    return make_float2((float)v.x, (float)v.y);
}

__global__ __launch_bounds__(256, 6)
void ssim_main(const float* __restrict__ pred, const float* __restrict__ targ,
               float* __restrict__ ws)
{
    // SoA column sums: Phase-A writes stride-1 b32 (conflict-free), Phase-B
    // reads stride-5 b32 (gcd(5,32)=1 -> conflict-free). 21 KB -> 6 blocks/CU.
    __shared__ float cs[4][2][CS_W];   // [comp][k][slot]: Sp, St, Spp+Stt, Spt
    __shared__ float red[4];

    const int tid   = threadIdx.x;
    const int plane = blockIdx.x % 96;    // vertical neighbors differ by 96 -> same XCD
    const int strip = blockIdx.x / 96;    // 0..15
    const int y0s   = strip * STRIP_H;
    const float* __restrict__ P = pred + plane * PLANE;
    const float* __restrict__ T = targ + plane * PLANE;

    // zero horizontal-halo cs slots once (first Phase-B read is after the
    // first barrier, which orders this write; Phase A never touches them)
    if (tid < 80) {
        int comp = tid / 20, k = (tid / 10) & 1, j = tid % 10;
        int s = (j < 5) ? j : (640 + j);   // {0..4, 645..649}
        cs[comp][k][s] = 0.f;
    }

    // ---- Register ring: 12-deep fp16x2 (p,t) history per column.
    //      Row y lives in slot (y - y0s + 7) mod 12. All indices static
    //      (6-way unrolled inner loop, outer rolled) -> stays in VGPRs.
    unsigned ring[3][12];
    float S[3][4];
#pragma unroll
    for (int c = 0; c < 3; ++c) {
        S[c][0]=S[c][1]=S[c][2]=S[c][3]=0.f;
        ring[c][0] = 0u;
    }

    // Bootstrap: rows [y0s-6, y0s+4] -> ring slots 1..11, column sums for
    // the window of output row y0s-1 (all arithmetic on quantized fp16)
#pragma unroll
    for (int c = 0; c < 3; ++c) {
        int x = tid + (c << 8);
        if (x < WIDTH) {
#pragma unroll
            for (int j = 0; j < 11; ++j) {
                int yy = y0s - 6 + j;
                unsigned h = 0u;
                if (yy >= 0) h = packh2(P[yy*WIDTH + x], T[yy*WIDTH + x]);
                ring[c][j + 1] = h;
                float2 v = unpackh2(h);
                S[c][0] += v.x;  S[c][1] += v.y;
                S[c][2] += v.x*v.x + v.y*v.y;
                S[c][3] += v.x*v.y;
            }
        } else {
#pragma unroll
            for (int j = 0; j < 11; ++j) ring[c][j + 1] = 0u;
        }
    }

    // prefetch registers for the two rows entering the window next group;
    // issued after Phase A, consumed at next group's Phase A -> latency
    // hidden under barrier + Phase B + barrier
    float pfP[3][2] = {{0.f,0.f},{0.f,0.f},{0.f,0.f}};
    float pfT[3][2] = {{0.f,0.f},{0.f,0.f},{0.f,0.f}};
    {   // group 0 entering rows (y0s+5, y0s+6 -- always in range)
#pragma unroll
        for (int c = 0; c < 3; ++c) {
            int x = tid + (c << 8);
            if (x < WIDTH) {
#pragma unroll
                for (int k = 0; k < 2; ++k) {
                    int yn = y0s + k + 5;
                    pfP[c][k] = P[yn*WIDTH + x];
                    pfT[c][k] = T[yn*WIDTH + x];
                }
            }
        }
    }

    float acc = 0.f;
    const float inv121 = 1.0f / 121.0f;
    const int r    = tid >> 6;
    const int lane = tid & 63;
    const int kb   = r & 1;
    const int base = ((r >> 1) * 320) + lane * 5;   // slots [base, base+14]

    auto eval = [&](float B0, float B1, float B2, float B3) {
        float mp  = B0 * inv121, mt = B1 * inv121;
        float mpp = mp*mp, mtt = mt*mt, mpt = mp*mt;
        float s2  = B2 * inv121 - mpp - mtt;   // sigma_p + sigma_t
        float spt = B3 * inv121 - mpt;         // sigma_pt
        float num = (2.f*mpt + SSIM_C1) * (2.f*spt + SSIM_C2);
        float den = (mpp + mtt + SSIM_C1) * (s2 + SSIM_C2);
        acc += num * __builtin_amdgcn_rcpf(den);
    };

#pragma clang loop unroll(disable)
    for (int go = 0; go < 2; ++go) {
#pragma unroll
        for (int u = 0; u < 6; ++u) {
            const int g = go * 6 + u;

            // ---- Phase A: advance 2 rows; ring slots are compile-time
            //      ((2u+k) and (2u+k+1)%12), so ring stays in registers
#pragma unroll
            for (int c = 0; c < 3; ++c) {
                int x = tid + (c << 8);
                if (x < WIDTH) {
#pragma unroll
                    for (int k = 0; k < 2; ++k) {
                        const int sNew = 2*u + k;            // write slot
                        const int sOld = (2*u + k + 1) % 12; // leaving row
                        unsigned hn = packh2(pfP[c][k], pfT[c][k]);
                        unsigned ho = ring[c][sOld];
                        ring[c][sNew] = hn;
                        float2 nq = unpackh2(hn);   // use quantized value
                        float2 o  = unpackh2(ho);
                        S[c][0] += nq.x - o.x;
                        S[c][1] += nq.y - o.y;
                        S[c][2] += nq.x*nq.x + nq.y*nq.y - o.x*o.x - o.y*o.y;
                        S[c][3] += nq.x*nq.y - o.x*o.y;
                        cs[0][k][x + 5] = S[c][0];
                        cs[1][k][x + 5] = S[c][1];
                        cs[2][k][x + 5] = S[c][2];
                        cs[3][k][x + 5] = S[c][3];
                    }
                }
            }

            // issue next group's entering-row loads now (pf regs just freed);
            // compiler's waitcnt lands before next Phase A's first use
            if (g + 1 < GROUPS) {
                const int y0 = y0s + ((g + 1) << 1);
#pragma unroll
                for (int c = 0; c < 3; ++c) {
                    int x = tid + (c << 8);
                    if (x < WIDTH) {
#pragma unroll
                        for (int k = 0; k < 2; ++k) {
                            int yn = y0 + k + 5;
                            bool v = (yn < HEIGHT);
                            pfP[c][k] = v ? P[yn*WIDTH + x] : 0.f;
                            pfT[c][k] = v ? T[yn*WIDTH + x] : 0.f;
                        }
                    }
                }
            }
            __syncthreads();

            // ---- Phase B: 4 waves = 2 rows x 2 halves; 5 px/lane; rolling
            //      11-window, all b32 at lane-stride 5 dwords (conflict-free);
            //      constant offsets from one base -> ds_read2_b32 merging
            {
                float B0=0.f, B1=0.f, B2=0.f, B3=0.f;
#pragma unroll
                for (int j = 0; j < 11; ++j) {
                    B0 += cs[0][kb][base + j];
                    B1 += cs[1][kb][base + j];
                    B2 += cs[2][kb][base + j];
                    B3 += cs[3][kb][base + j];
                }
                eval(B0, B1, B2, B3);
#pragma unroll
                for (int i = 1; i < 5; ++i) {
                    B0 += cs[0][kb][base + 10 + i] - cs[0][kb][base + i - 1];
                    B1 += cs[1][kb][base + 10 + i] - cs[1][kb][base + i - 1];
                    B2 += cs[2][kb][base + 10 + i] - cs[2][kb][base + i - 1];
                    B3 += cs[3][kb][base + 10 + i] - cs[3][kb][base + i - 1];
                    eval(B0, B1, B2, B3);
                }
            }
            __syncthreads();
        }
    }

    // ---- block reduction -> one plain store per block (no atomics)
#pragma unroll
    for (int off = 32; off >= 1; off >>= 1)
        acc += __shfl_down(acc, off);
    if ((tid & 63) == 0) red[tid >> 6] = acc;
    __syncthreads();
    if (tid == 0)
        ws[blockIdx.x] = red[0] + red[1] + red[2] + red[3];
}

__global__ void ssim_reduce(const float* __restrict__ ws, float* __restrict__ out)
{
    __shared__ float red[4];
    const int tid = threadIdx.x;
    float s = 0.f;
#pragma unroll
    for (int i = 0; i < 6; ++i) s += ws[tid + (i << 8)];
#pragma unroll
    for (int off = 32; off >= 1; off >>= 1)
        s += __shfl_down(s, off);
    if ((tid & 63) == 0) red[tid >> 6] = s;
    __syncthreads();
    if (tid == 0)
        out[0] = 1.0f - (red[0] + red[1] + red[2] + red[3]) * INV_N;
}

extern "C" void kernel_launch(void* const* d_in, const int* in_sizes, int n_in,
                              void* d_out, int out_size, void* d_ws, size_t ws_size,
                              hipStream_t stream) {
    const float* pred = (const float*)d_in[0];
    const float* targ = (const float*)d_in[1];
    float* out = (float*)d_out;
    float* ws  = (float*)d_ws;          // 1536 floats of partial sums
    ssim_main<<<NBLK, 256, 0, stream>>>(pred, targ, ws);
    ssim_reduce<<<1, 256, 0, stream>>>(ws, out);
}

// Round 3
// 222.262 us; speedup vs baseline: 3.3842x; 3.3842x over previous
//
#include <hip/hip_runtime.h>
#include <hip/hip_fp16.h>

#define WIDTH   640
#define HEIGHT  384
#define PLANE   (WIDTH*HEIGHT)
#define STRIP_H 48
#define NSTRIP  8                 /* 384/48 */
#define GROUPS  24                /* STRIP_H/2 */
#define NBLK    (96*NSTRIP)       /* 768 = 3 blocks/CU exactly */
#define CS_W    656               /* slots 0..649 used, slot = x+5 */
#define SSIM_C1 1.0e-4f
#define SSIM_C2 9.0e-4f
#define INV_N   (1.0f/23592960.0f)

__device__ __forceinline__ __half2 packh2(float a, float b) {
    // single v_cvt_pkrtz_f16_f32; rtz quantization is consistent add/sub so no drift
    __fp16 __attribute__((ext_vector_type(2))) v = __builtin_amdgcn_cvt_pkrtz(a, b);
    __half2 r;
    __builtin_memcpy(&r, &v, sizeof(r));
    return r;
}

__global__ __launch_bounds__(256, 3)
void ssim_main(const float* __restrict__ pred, const float* __restrict__ targ,
               float* __restrict__ ws)
{
    // LDS ring of raw fp16 (p,t) pairs: stride-1 dword access, conflict-free.
    // SoA column sums: Phase-A writes stride-1 b32 (free), Phase-B reads
    // stride-5 b32 (gcd(5,32)=1 -> 2-way, free). Proven in round 1: SoA drops
    // SQ_LDS_BANK_CONFLICT 2.4e7 -> ~3e3.
    __shared__ __half2 ring[11][WIDTH];   // 28.2 KB
    __shared__ float   cs[4][2][CS_W];    // [comp][k][slot]: Sp, St, Spp+Stt, Spt (21 KB)
    __shared__ float   red[4];

    const int tid   = threadIdx.x;
    const int plane = blockIdx.x % 96;      // vertical neighbors differ by 96 -> same XCD
    const int strip = blockIdx.x / 96;      // 0..7
    const int y0s   = strip * STRIP_H;
    const float* __restrict__ P = pred + plane * PLANE;
    const float* __restrict__ T = targ + plane * PLANE;

    // zero horizontal-halo cs slots once (Phase A never touches them; first
    // Phase-B read is after the first barrier, which orders this write)
    if (tid < 80) {
        int comp = tid / 20, k = (tid / 10) & 1, j = tid % 10;
        int s = (j < 5) ? j : (640 + j);    // {0..4, 645..649}
        cs[comp][k][s] = 0.f;
    }

    // ---- Bootstrap: stage rows [y0s-6, y0s+4] into ring, build column sums
    //      for output row y0s-1 (all arithmetic on the quantized fp16 values)
    float S[3][4];
#pragma unroll
    for (int c = 0; c < 3; ++c) { S[c][0]=S[c][1]=S[c][2]=S[c][3]=0.f; }

#pragma unroll
    for (int c = 0; c < 3; ++c) {
        int x = tid + (c << 8);
        if (x < WIDTH) {
            for (int j = 0; j < 11; ++j) {
                int yy = y0s - 6 + j;
                __half2 h = (yy >= 0) ? packh2(P[yy*WIDTH+x], T[yy*WIDTH+x])
                                      : packh2(0.f, 0.f);
                ring[j][x] = h;
                float2 v = __half22float2(h);
                S[c][0] += v.x;  S[c][1] += v.y;
                S[c][2] += v.x*v.x + v.y*v.y;
                S[c][3] += v.x*v.y;
            }
        }
    }

    // prefetch registers for the two rows entering the window each group
    float pfP[3][2], pfT[3][2];
    auto do_prefetch = [&](int gg) {
        const int y0 = y0s + (gg << 1);
#pragma unroll
        for (int c = 0; c < 3; ++c) {
            int x = tid + (c << 8);
            if (x < WIDTH) {
#pragma unroll
                for (int k = 0; k < 2; ++k) {
                    int yn = y0 + k + 5;
                    bool v = (yn < HEIGHT);
                    pfP[c][k] = v ? P[yn*WIDTH + x] : 0.f;
                    pfT[c][k] = v ? T[yn*WIDTH + x] : 0.f;
                }
            }
        }
    };
    do_prefetch(0);

    float acc = 0.f;
    const float inv121 = 1.0f / 121.0f;
    const int r    = tid >> 6;
    const int lane = tid & 63;
    const int kb   = r & 1;
    const int base = ((r >> 1) * 320) + lane * 5;   // slots [base, base+14]
    int rs = 0;   // ring slot of the row leaving/entering at k=0 of this group

    for (int g = 0; g < GROUPS; ++g) {
        // consume this group's prefetched rows, then immediately issue next
        // group's loads -> VMEM latency overlaps rest of A + barrier + B
        float cP[3][2], cT[3][2];
#pragma unroll
        for (int c = 0; c < 3; ++c)
#pragma unroll
            for (int k = 0; k < 2; ++k) { cP[c][k] = pfP[c][k]; cT[c][k] = pfT[c][k]; }

        if (g + 1 < GROUPS) do_prefetch(g + 1);

        // ---- Phase A: advance 2 rows; subtract old from LDS ring, add new
#pragma unroll
        for (int c = 0; c < 3; ++c) {
            int x = tid + (c << 8);
            if (x < WIDTH) {
#pragma unroll
                for (int k = 0; k < 2; ++k) {
                    int slot = rs + k; if (slot >= 11) slot -= 11;
                    float nx = cP[c][k], ny = cT[c][k];
                    __half2 hn = packh2(nx, ny);
                    __half2 ho = ring[slot][x];
                    ring[slot][x] = hn;
                    float2 nq = __half22float2(hn);   // use quantized value
                    float2 o  = __half22float2(ho);
                    S[c][0] += nq.x - o.x;
                    S[c][1] += nq.y - o.y;
                    S[c][2] += nq.x*nq.x + nq.y*nq.y - o.x*o.x - o.y*o.y;
                    S[c][3] += nq.x*nq.y - o.x*o.y;
                    cs[0][k][x + 5] = S[c][0];
                    cs[1][k][x + 5] = S[c][1];
                    cs[2][k][x + 5] = S[c][2];
                    cs[3][k][x + 5] = S[c][3];
                }
            }
        }
        __syncthreads();

        // ---- Phase B: 4 waves = 2 rows x 2 halves; 5 px/lane; rolling
        //      11-window, all b32 at lane-stride 5 dwords (conflict-free);
        //      constant offsets from one base -> ds_read2_b32 merging
        {
            float B0=0.f, B1=0.f, B2=0.f, B3=0.f;
#pragma unroll
            for (int j = 0; j < 11; ++j) {
                B0 += cs[0][kb][base + j];
                B1 += cs[1][kb][base + j];
                B2 += cs[2][kb][base + j];
                B3 += cs[3][kb][base + j];
            }
#pragma unroll
            for (int i = 0; i < 5; ++i) {
                if (i > 0) {
                    B0 += cs[0][kb][base + 10 + i] - cs[0][kb][base + i - 1];
                    B1 += cs[1][kb][base + 10 + i] - cs[1][kb][base + i - 1];
                    B2 += cs[2][kb][base + 10 + i] - cs[2][kb][base + i - 1];
                    B3 += cs[3][kb][base + 10 + i] - cs[3][kb][base + i - 1];
                }
                float mp  = B0 * inv121, mt = B1 * inv121;
                float mpp = mp*mp, mtt = mt*mt, mpt = mp*mt;
                float s2  = B2 * inv121 - mpp - mtt;   // sigma_p + sigma_t
                float spt = B3 * inv121 - mpt;         // sigma_pt
                float num = (2.f*mpt + SSIM_C1) * (2.f*spt + SSIM_C2);
                float den = (mpp + mtt + SSIM_C1) * (s2 + SSIM_C2);
                acc += num * __builtin_amdgcn_rcpf(den);
            }
        }
        __syncthreads();

        rs += 2; if (rs >= 11) rs -= 11;
    }

    // ---- block reduction -> one plain store per block (no atomics)
#pragma unroll
    for (int off = 32; off >= 1; off >>= 1)
        acc += __shfl_down(acc, off);
    if ((tid & 63) == 0) red[tid >> 6] = acc;
    __syncthreads();
    if (tid == 0)
        ws[blockIdx.x] = red[0] + red[1] + red[2] + red[3];
}

__global__ void ssim_reduce(const float* __restrict__ ws, float* __restrict__ out)
{
    __shared__ float red[4];
    const int tid = threadIdx.x;
    float s = ws[tid] + ws[tid + 256] + ws[tid + 512];
#pragma unroll
    for (int off = 32; off >= 1; off >>= 1)
        s += __shfl_down(s, off);
    if ((tid & 63) == 0) red[tid >> 6] = s;
    __syncthreads();
    if (tid == 0)
        out[0] = 1.0f - (red[0] + red[1] + red[2] + red[3]) * INV_N;
}

extern "C" void kernel_launch(void* const* d_in, const int* in_sizes, int n_in,
                              void* d_out, int out_size, void* d_ws, size_t ws_size,
                              hipStream_t stream) {
    const float* pred = (const float*)d_in[0];
    const float* targ = (const float*)d_in[1];
    float* out = (float*)d_out;
    float* ws  = (float*)d_ws;          // 768 floats of partial sums
    ssim_main<<<NBLK, 256, 0, stream>>>(pred, targ, ws);
    ssim_reduce<<<1, 256, 0, stream>>>(ws, out);
}